// Round 1
// baseline (46505.310 us; speedup 1.0000x reference)
//
#include <hip/hip_runtime.h>
#include <math.h>

#define B 64
#define T_READ 128
#define L_WRITE 32
#define TT 160          // T_READ + L_WRITE
#define D 256
#define R 1024
#define N 512
#define M 128
#define K1K 1408        // (D + M) + R
#define HD 524
#define K5K 1152        // R + M
#define EPS 1e-8f
#define KC 64

__device__ __forceinline__ float sigmoidf(float x){ return 1.0f/(1.0f+expf(-x)); }
__device__ __forceinline__ float softplusf(float x){ return (x > 20.f) ? x : log1pf(expf(x)); }

// ---------------- init state ----------------
__global__ void k_init(float* h, float* c, float* reads, float* w_r, float* w_w, float* Mem){
    int idx = blockIdx.x*blockDim.x + threadIdx.x;
    int stride = gridDim.x*blockDim.x;
    for (int i = idx; i < B*N*M; i += stride) Mem[i] = 1e-6f;
    for (int i = idx; i < B*R;   i += stride){ h[i]=0.f; c[i]=0.f; }
    for (int i = idx; i < B*M;   i += stride) reads[i]=0.f;
    for (int i = idx; i < B*N;   i += stride){ w_r[i]=1.0f/(float)N; w_w[i]=1.0f/(float)N; }
}

// ---------------- K1: z = [x_t, reads] @ W_lstm + h @ U_lstm + b ----------------
// grid 256 blocks, 256 thr; block computes 64 batches x 16 cols of z
__global__ __launch_bounds__(256) void k1_zgemm(
    const float* __restrict__ x, const float* __restrict__ reads, const float* __restrict__ h,
    const float* __restrict__ Wl, const float* __restrict__ Ul, const float* __restrict__ bias_l,
    float* __restrict__ z, int t)
{
    __shared__ float As[KC][64+1];
    const int tid = threadIdx.x;
    const int b  = tid & 63;
    const int jq = tid >> 6;               // 0..3
    const int j0 = blockIdx.x*16 + jq*4;
    float acc0=0.f, acc1=0.f, acc2=0.f, acc3=0.f;
    const int ch0 = (t < T_READ) ? 0 : 4;  // write phase: x_t == 0, skip its chunks
    for (int ch = ch0; ch < K1K/KC; ++ch){
        const int kc = ch*KC;
        // stage A chunk [64 k][64 b], coalesced in k
        for (int lin = tid; lin < 64*64; lin += 256){
            int kl = lin & 63, bl = lin >> 6;
            int k = kc + kl;
            float v;
            if (k < D)            v = x[((size_t)bl*T_READ + t)*D + k];
            else if (k < D + M)   v = reads[bl*M + (k - D)];
            else                  v = h[(size_t)bl*R + (k - D - M)];
            As[kl][bl] = v;
        }
        __syncthreads();
        const float* wrow = (ch < 6) ? (Wl + (size_t)kc*4096) : (Ul + (size_t)(kc-384)*4096);
        #pragma unroll 8
        for (int kl = 0; kl < KC; ++kl){
            float a = As[kl][b];
            float4 wv = *reinterpret_cast<const float4*>(wrow + (size_t)kl*4096 + j0);
            acc0 += a*wv.x; acc1 += a*wv.y; acc2 += a*wv.z; acc3 += a*wv.w;
        }
        __syncthreads();
    }
    float4 bv = *reinterpret_cast<const float4*>(bias_l + j0);
    float4 ov; ov.x = acc0+bv.x; ov.y = acc1+bv.y; ov.z = acc2+bv.z; ov.w = acc3+bv.w;
    *reinterpret_cast<float4*>(z + (size_t)b*4096 + j0) = ov;
}

// ---------------- K2: LSTM cell update ----------------
__global__ __launch_bounds__(256) void k2_gates(const float* __restrict__ z,
                                                float* __restrict__ c, float* __restrict__ h){
    int idx = blockIdx.x*256 + threadIdx.x;      // 0..B*R-1
    int b = idx >> 10, r = idx & 1023;
    const float* zb = z + (size_t)b*4096;
    float zi = zb[r], zf = zb[r+1024], zg = zb[r+2048], zo = zb[r+3072];
    float cn = sigmoidf(zf)*c[idx] + sigmoidf(zi)*tanhf(zg);
    float hn = sigmoidf(zo)*tanhf(cn);
    c[idx] = cn; h[idx] = hn;
}

// ---------------- K3: p = h @ W_heads + b_heads (+ khat/erase/add epilogue) ----------------
// grid 131 blocks, 256 thr; block computes 64 batches x 4 cols
__global__ __launch_bounds__(256) void k3_heads(
    const float* __restrict__ h, const float* __restrict__ Wh, const float* __restrict__ bh,
    float* __restrict__ p, float* __restrict__ khat, float* __restrict__ ea)
{
    __shared__ float Hs[KC][64+1];
    const int tid = threadIdx.x;
    const int b  = tid & 63;
    const int jq = tid >> 6;
    const int j  = blockIdx.x*4 + jq;
    float acc = 0.f;
    for (int ch = 0; ch < R/KC; ++ch){
        const int kc = ch*KC;
        for (int lin = tid; lin < 64*64; lin += 256){
            int kl = lin & 63, bl = lin >> 6;
            Hs[kl][bl] = h[(size_t)bl*R + kc + kl];
        }
        __syncthreads();
        #pragma unroll 8
        for (int kl = 0; kl < KC; ++kl)
            acc += Hs[kl][b] * Wh[(size_t)(kc+kl)*HD + j];
        __syncthreads();
    }
    float v = acc + bh[j];
    p[(size_t)b*HD + j] = v;
    if (j < 128)                     khat[(b*2+0)*128 + j]        = tanhf(v);
    else if (j >= 134 && j < 262)    khat[(b*2+1)*128 + (j-134)]  = tanhf(v);
    else if (j >= 268 && j < 396)    ea[(b*2+0)*128 + (j-268)]    = sigmoidf(v);
    else if (j >= 396)               ea[(b*2+1)*128 + (j-396)]    = tanhf(v);
}

// ---------------- K4a: Mem row norms + dot(Mem, khat) for both heads ----------------
// one wave per (b,n); grid B*N/4 blocks of 256
__global__ __launch_bounds__(256) void k4a_dots(
    const float* __restrict__ Mem, const float* __restrict__ khat,
    float* __restrict__ mnorm, float* __restrict__ dots)
{
    int wid  = blockIdx.x*4 + (threadIdx.x >> 6);
    int lane = threadIdx.x & 63;
    int b = wid >> 9, n = wid & 511;
    const float* mrow = Mem + (size_t)(b*N + n)*M;
    float2 mv = *reinterpret_cast<const float2*>(mrow + lane*2);
    float2 kr = *reinterpret_cast<const float2*>(khat + (b*2+0)*128 + lane*2);
    float2 kw = *reinterpret_cast<const float2*>(khat + (b*2+1)*128 + lane*2);
    float s2 = mv.x*mv.x + mv.y*mv.y;
    float dr = mv.x*kr.x + mv.y*kr.y;
    float dw = mv.x*kw.x + mv.y*kw.y;
    #pragma unroll
    for (int off = 32; off; off >>= 1){
        s2 += __shfl_xor(s2, off);
        dr += __shfl_xor(dr, off);
        dw += __shfl_xor(dw, off);
    }
    if (lane == 0){
        mnorm[b*N + n] = sqrtf(s2);
        dots[(b*2+0)*N + n] = dr;
        dots[(b*2+1)*N + n] = dw;
    }
}

// ---------------- K4b: full addressing for one (b,head) per block ----------------
__device__ __forceinline__ float blk_sum(float v, float* red, int n){
    red[n] = v; __syncthreads();
    #pragma unroll
    for (int s = 256; s > 0; s >>= 1){ if (n < s) red[n] += red[n+s]; __syncthreads(); }
    float r = red[0]; __syncthreads();
    return r;
}
__device__ __forceinline__ float blk_max(float v, float* red, int n){
    red[n] = v; __syncthreads();
    #pragma unroll
    for (int s = 256; s > 0; s >>= 1){ if (n < s) red[n] = fmaxf(red[n], red[n+s]); __syncthreads(); }
    float r = red[0]; __syncthreads();
    return r;
}

__global__ __launch_bounds__(512) void k4b_address(
    const float* __restrict__ p, const float* __restrict__ khat,
    const float* __restrict__ mnorm, const float* __restrict__ dots,
    float* __restrict__ w_r, float* __restrict__ w_w)
{
    __shared__ float red[512];
    __shared__ float wg[512];
    const int b = blockIdx.x >> 1, head = blockIdx.x & 1;
    const int n = threadIdx.x;
    const int offs = head ? 134 : 0;
    const float* pb = p + (size_t)b*HD;

    // ||tanh(k)||
    float kv = (n < 128) ? khat[(b*2+head)*128 + n] : 0.f;
    float kn = sqrtf(blk_sum(kv*kv, red, n));

    float beta  = softplusf(pb[offs+128]);
    float g     = sigmoidf(pb[offs+129]);
    float s0r = pb[offs+130], s1r = pb[offs+131], s2r = pb[offs+132];
    float gamma = 1.0f + softplusf(pb[offs+133]);
    float smx = fmaxf(s0r, fmaxf(s1r, s2r));
    float e0 = expf(s0r-smx), e1 = expf(s1r-smx), e2 = expf(s2r-smx);
    float esum = e0+e1+e2;
    float s0 = e0/esum, s1 = e1/esum, s2 = e2/esum;

    float sim = dots[(b*2+head)*N + n] / (mnorm[b*N + n]*kn + EPS);
    float a = beta * sim;
    float amax = blk_max(a, red, n);
    float ev = expf(a - amax);
    float wc = ev / blk_sum(ev, red, n);

    float* wbuf = head ? w_w : w_r;
    float wprev = wbuf[b*N + n];
    float wgv = g*wc + (1.0f - g)*wprev;
    wg[n] = wgv; __syncthreads();
    float wsv = s0*wg[(n+1)&511] + s1*wgv + s2*wg[(n-1)&511];
    float wp = powf(wsv + EPS, gamma);
    float wsum = blk_sum(wp, red, n);
    wbuf[b*N + n] = wp / wsum;
}

// ---------------- K4c: reads = w_r . Mem (old) ; Mem erase/add update ----------------
// one block per batch
__global__ __launch_bounds__(256) void k4c_rw(
    float* __restrict__ Mem, const float* __restrict__ w_r, const float* __restrict__ w_w,
    const float* __restrict__ ea, float* __restrict__ reads)
{
    __shared__ float red[256];
    const int b = blockIdx.x;
    const int m = threadIdx.x & 127, ng = threadIdx.x >> 7;
    const float e  = ea[(b*2+0)*128 + m];
    const float ad = ea[(b*2+1)*128 + m];
    float racc = 0.f;
    for (int n = ng; n < N; n += 2){
        float wr = w_r[b*N + n], ww = w_w[b*N + n];
        size_t idx = (size_t)(b*N + n)*M + m;
        float v = Mem[idx];
        racc += wr * v;
        Mem[idx] = v*(1.0f - ww*e) + ww*ad;
    }
    red[threadIdx.x] = racc; __syncthreads();
    if (ng == 0) reads[b*M + m] = red[m] + red[m+128];
}

// ---------------- K5: out = sigmoid([h, reads] @ W_out + b_out) (write phase only) ----------------
// grid 64 blocks (4 cols each), 256 thr
__global__ __launch_bounds__(256) void k5_out(
    const float* __restrict__ h, const float* __restrict__ reads,
    const float* __restrict__ Wo, const float* __restrict__ bo,
    float* __restrict__ out, int t)
{
    __shared__ float As[KC][64+1];
    const int tid = threadIdx.x;
    const int b  = tid & 63;
    const int jq = tid >> 6;
    const int j  = blockIdx.x*4 + jq;
    float acc = 0.f;
    for (int ch = 0; ch < K5K/KC; ++ch){
        const int kc = ch*KC;
        for (int lin = tid; lin < 64*64; lin += 256){
            int kl = lin & 63, bl = lin >> 6;
            int k = kc + kl;
            As[kl][bl] = (k < R) ? h[(size_t)bl*R + k] : reads[bl*M + (k - R)];
        }
        __syncthreads();
        #pragma unroll 8
        for (int kl = 0; kl < KC; ++kl)
            acc += As[kl][b] * Wo[(size_t)(kc+kl)*D + j];
        __syncthreads();
    }
    float v = sigmoidf(acc + bo[j]);
    out[((size_t)b*L_WRITE + (t - T_READ))*D + j] = v;
}

extern "C" void kernel_launch(void* const* d_in, const int* in_sizes, int n_in,
                              void* d_out, int out_size, void* d_ws, size_t ws_size,
                              hipStream_t stream)
{
    const float* x   = (const float*)d_in[0];
    const float* Wl  = (const float*)d_in[1];
    const float* Ul  = (const float*)d_in[2];
    const float* bl  = (const float*)d_in[3];
    const float* Wh  = (const float*)d_in[4];
    const float* bh  = (const float*)d_in[5];
    const float* Wo  = (const float*)d_in[6];
    const float* bo  = (const float*)d_in[7];
    float* out = (float*)d_out;

    float* ws = (float*)d_ws;
    float* h     = ws;  ws += B*R;
    float* c     = ws;  ws += B*R;
    float* reads = ws;  ws += B*M;
    float* w_r   = ws;  ws += B*N;
    float* w_w   = ws;  ws += B*N;
    float* Mem   = ws;  ws += B*N*M;
    float* z     = ws;  ws += B*4*R;
    float* p     = ws;  ws += B*HD;
    float* khat  = ws;  ws += B*2*M;
    float* ea    = ws;  ws += B*2*M;
    float* mnorm = ws;  ws += B*N;
    float* dots  = ws;  ws += B*2*N;

    hipLaunchKernelGGL(k_init, dim3(2048), dim3(256), 0, stream, h, c, reads, w_r, w_w, Mem);

    for (int t = 0; t < TT; ++t){
        hipLaunchKernelGGL(k1_zgemm,   dim3(256),  dim3(256), 0, stream, x, reads, h, Wl, Ul, bl, z, t);
        hipLaunchKernelGGL(k2_gates,   dim3(256),  dim3(256), 0, stream, z, c, h);
        hipLaunchKernelGGL(k3_heads,   dim3(131),  dim3(256), 0, stream, h, Wh, bh, p, khat, ea);
        hipLaunchKernelGGL(k4a_dots,   dim3(8192), dim3(256), 0, stream, Mem, khat, mnorm, dots);
        hipLaunchKernelGGL(k4b_address,dim3(128),  dim3(512), 0, stream, p, khat, mnorm, dots, w_r, w_w);
        hipLaunchKernelGGL(k4c_rw,     dim3(64),   dim3(256), 0, stream, Mem, w_r, w_w, ea, reads);
        if (t >= T_READ)
            hipLaunchKernelGGL(k5_out, dim3(64),   dim3(256), 0, stream, h, reads, Wo, bo, out, t);
    }
}

// Round 2
// 18954.536 us; speedup vs baseline: 2.4535x; 2.4535x over previous
//
#include <hip/hip_runtime.h>
#include <math.h>

#define B 64
#define T_READ 128
#define L_WRITE 32
#define TT 160
#define D 256
#define R 1024
#define N 512
#define M 128
#define K1K 1408        // 256 x + 128 reads + 1024 h
#define HD 524
#define K5K 1152
#define EPS 1e-8f

__device__ __forceinline__ float sigmoidf(float x){ return 1.0f/(1.0f+expf(-x)); }
__device__ __forceinline__ float softplusf(float x){ return (x > 20.f) ? x : log1pf(expf(x)); }

// ---------- one-time: transpose x -> xT[t][k][b] ----------
__global__ __launch_bounds__(256) void kx_transpose(const float* __restrict__ x, float* __restrict__ xT){
    __shared__ float tile[64][65];
    const int t = blockIdx.x >> 2, k0 = (blockIdx.x & 3)*64;
    #pragma unroll
    for (int rep = 0; rep < 16; ++rep){
        int idx = rep*256 + threadIdx.x;
        int bl = idx >> 6, kl = idx & 63;
        tile[bl][kl] = x[((size_t)bl*T_READ + t)*D + k0 + kl];
    }
    __syncthreads();
    #pragma unroll
    for (int rep = 0; rep < 16; ++rep){
        int idx = rep*256 + threadIdx.x;
        int kl = idx >> 6, bl = idx & 63;
        xT[((size_t)t*D + k0 + kl)*64 + bl] = tile[bl][kl];
    }
}

// ---------- one-time: init state ----------
__global__ void k_init(const float* __restrict__ xT, float* At, float* c_t,
                       float* w_r, float* w_w, float* Mem){
    int idx = blockIdx.x*blockDim.x + threadIdx.x;
    int stride = gridDim.x*blockDim.x;
    for (int i = idx; i < B*N*M; i += stride) Mem[i] = 1e-6f;
    for (int i = idx; i < K1K*64; i += stride) At[i] = (i < D*64) ? xT[i] : 0.f; // x rows for t=0, rest 0
    for (int i = idx; i < R*64; i += stride) c_t[i] = 0.f;
    for (int i = idx; i < B*N; i += stride){ w_r[i] = 1.f/(float)N; w_w[i] = 1.f/(float)N; }
}

// ---------- K1: z partials. grid 512 = 128 colblocks x 4 ksplit, 256 thr ----------
__global__ __launch_bounds__(256) void k1_zgemm(
    const float* __restrict__ At, const float* __restrict__ Wl, const float* __restrict__ Ul,
    float* __restrict__ z_part)
{
    const int lane = threadIdx.x & 63;
    const int w    = threadIdx.x >> 6;
    const int cb   = blockIdx.x >> 2;
    const int ks   = blockIdx.x & 3;
    const int j0   = cb*32 + w*8;
    const int k0   = ks*352, kend = k0 + 352;
    float acc[8] = {0.f,0.f,0.f,0.f,0.f,0.f,0.f,0.f};
    #pragma unroll 2
    for (int k = k0; k < kend; ++k){
        float a = At[(size_t)k*64 + lane];
        const float* wrow = (k < 384) ? (Wl + (size_t)k*4096) : (Ul + (size_t)(k-384)*4096);
        float4 w0 = *reinterpret_cast<const float4*>(wrow + j0);
        float4 w1 = *reinterpret_cast<const float4*>(wrow + j0 + 4);
        acc[0] += a*w0.x; acc[1] += a*w0.y; acc[2] += a*w0.z; acc[3] += a*w0.w;
        acc[4] += a*w1.x; acc[5] += a*w1.y; acc[6] += a*w1.z; acc[7] += a*w1.w;
    }
    #pragma unroll
    for (int i = 0; i < 8; ++i)
        z_part[((size_t)ks*4096 + (j0+i))*64 + lane] = acc[i];
}

// ---------- K2: combine z partials + LSTM cell. grid 256, 256 thr ----------
__global__ __launch_bounds__(256) void k2_gates(
    const float* __restrict__ zp, const float* __restrict__ bl,
    float* __restrict__ c_t, float* __restrict__ At, float* __restrict__ hist, int t)
{
    const int b = threadIdx.x & 63;
    const int r = blockIdx.x*4 + (threadIdx.x >> 6);
    float g4[4];
    #pragma unroll
    for (int g = 0; g < 4; ++g){
        int col = r + g*1024;
        float s = bl[col];
        #pragma unroll
        for (int ks = 0; ks < 4; ++ks) s += zp[((size_t)ks*4096 + col)*64 + b];
        g4[g] = s;
    }
    float cn = sigmoidf(g4[1])*c_t[r*64+b] + sigmoidf(g4[0])*tanhf(g4[2]);
    float hn = sigmoidf(g4[3])*tanhf(cn);
    c_t[r*64+b] = cn;
    At[(size_t)(384 + r)*64 + b] = hn;
    if (t >= T_READ) hist[((size_t)(t-T_READ)*K5K + r)*64 + b] = hn;
}

// ---------- K3: head-param partials pp[8][b][524]. grid 262, 256 thr ----------
__global__ __launch_bounds__(256) void k3_heads(
    const float* __restrict__ At, const float* __restrict__ Wh, float* __restrict__ pp)
{
    const int lane = threadIdx.x & 63;
    const int wid  = blockIdx.x*4 + (threadIdx.x >> 6);   // 0..1047
    const int cg = wid % 131, ks = wid / 131;
    const int j0 = cg*4;
    const int k0 = ks*128;
    float ax=0.f, ay=0.f, az=0.f, aw=0.f;
    #pragma unroll 4
    for (int k = k0; k < k0+128; ++k){
        float a = At[(size_t)(384 + k)*64 + lane];
        float4 wv = *reinterpret_cast<const float4*>(Wh + (size_t)k*HD + j0);
        ax += a*wv.x; ay += a*wv.y; az += a*wv.z; aw += a*wv.w;
    }
    float* dst = pp + ((size_t)ks*64 + lane)*HD + j0;
    dst[0]=ax; dst[1]=ay; dst[2]=az; dst[3]=aw;
}

// ---------- K4a: Mem row norms + content dots (khat recomputed from pp). grid 8192, 256 thr ----------
__global__ __launch_bounds__(256) void k4a_dots(
    const float* __restrict__ Mem, const float* __restrict__ pp, const float* __restrict__ bh,
    float* __restrict__ mnorm, float* __restrict__ dots)
{
    __shared__ float kh[256];
    const int b = blockIdx.x >> 7;
    {
        int i = threadIdx.x;
        int head = i >> 7, m = i & 127;
        int col = head ? (134 + m) : m;
        float v = bh[col];
        #pragma unroll
        for (int ks = 0; ks < 8; ++ks) v += pp[((size_t)ks*64 + b)*HD + col];
        kh[i] = tanhf(v);
    }
    __syncthreads();
    const int wid  = blockIdx.x*4 + (threadIdx.x >> 6);
    const int lane = threadIdx.x & 63;
    const int n = wid & 511;
    const float* mrow = Mem + (size_t)(b*N + n)*M;
    float2 mv = *reinterpret_cast<const float2*>(mrow + lane*2);
    float2 kr = *reinterpret_cast<const float2*>(&kh[lane*2]);
    float2 kw = *reinterpret_cast<const float2*>(&kh[128 + lane*2]);
    float s2 = mv.x*mv.x + mv.y*mv.y;
    float dr = mv.x*kr.x + mv.y*kr.y;
    float dw = mv.x*kw.x + mv.y*kw.y;
    #pragma unroll
    for (int off = 32; off; off >>= 1){
        s2 += __shfl_xor(s2, off);
        dr += __shfl_xor(dr, off);
        dw += __shfl_xor(dw, off);
    }
    if (lane == 0){
        mnorm[b*N + n] = sqrtf(s2);
        dots[(b*2+0)*N + n] = dr;
        dots[(b*2+1)*N + n] = dw;
    }
}

// ---------- K4b: addressing. grid 128 (b,head), 512 thr ----------
__device__ __forceinline__ float blk_sum(float v, float* red, int n){
    red[n] = v; __syncthreads();
    #pragma unroll
    for (int s = 256; s > 0; s >>= 1){ if (n < s) red[n] += red[n+s]; __syncthreads(); }
    float r = red[0]; __syncthreads();
    return r;
}
__device__ __forceinline__ float blk_max(float v, float* red, int n){
    red[n] = v; __syncthreads();
    #pragma unroll
    for (int s = 256; s > 0; s >>= 1){ if (n < s) red[n] = fmaxf(red[n], red[n+s]); __syncthreads(); }
    float r = red[0]; __syncthreads();
    return r;
}

__global__ __launch_bounds__(512) void k4b_address(
    const float* __restrict__ pp, const float* __restrict__ bh,
    const float* __restrict__ mnorm, const float* __restrict__ dots,
    float* __restrict__ w_r, float* __restrict__ w_w)
{
    __shared__ float red[512];
    __shared__ float wg[512];
    const int b = blockIdx.x >> 1, head = blockIdx.x & 1;
    const int n = threadIdx.x;
    const int offs = head ? 134 : 0;

    float kv = 0.f;
    if (n < 128){
        float v = bh[offs + n];
        #pragma unroll
        for (int ks = 0; ks < 8; ++ks) v += pp[((size_t)ks*64 + b)*HD + offs + n];
        kv = tanhf(v);
    }
    float kn = sqrtf(blk_sum(kv*kv, red, n));

    float sc[6];
    #pragma unroll
    for (int i = 0; i < 6; ++i){
        float v = bh[offs + 128 + i];
        #pragma unroll
        for (int ks = 0; ks < 8; ++ks) v += pp[((size_t)ks*64 + b)*HD + offs + 128 + i];
        sc[i] = v;
    }
    float beta  = softplusf(sc[0]);
    float g     = sigmoidf(sc[1]);
    float gamma = 1.0f + softplusf(sc[5]);
    float smx = fmaxf(sc[2], fmaxf(sc[3], sc[4]));
    float e0 = expf(sc[2]-smx), e1 = expf(sc[3]-smx), e2 = expf(sc[4]-smx);
    float esum = e0+e1+e2;
    float s0 = e0/esum, s1 = e1/esum, s2 = e2/esum;

    float sim = dots[(b*2+head)*N + n] / (mnorm[b*N + n]*kn + EPS);
    float a = beta * sim;
    float amax = blk_max(a, red, n);
    float ev = expf(a - amax);
    float wc = ev / blk_sum(ev, red, n);

    float* wbuf = head ? w_w : w_r;
    float wprev = wbuf[b*N + n];
    float wgv = g*wc + (1.0f - g)*wprev;
    wg[n] = wgv; __syncthreads();
    float wsv = s0*wg[(n+1)&511] + s1*wgv + s2*wg[(n-1)&511];
    float wp = powf(wsv + EPS, gamma);
    float wsum = blk_sum(wp, red, n);
    wbuf[b*N + n] = wp / wsum;
}

// ---------- K4c: read (old Mem) + erase/add update. grid 512 = 64 b x 8 ngroups, 256 thr ----------
__global__ __launch_bounds__(256) void k4c_rw(
    float* __restrict__ Mem, const float* __restrict__ w_r, const float* __restrict__ w_w,
    const float* __restrict__ pp, const float* __restrict__ bh, float* __restrict__ reads_part)
{
    __shared__ float red[256];
    const int b = blockIdx.x >> 3, ng = blockIdx.x & 7;
    const int m = threadIdx.x & 127, hh = threadIdx.x >> 7;
    float ev = bh[268+m], av = bh[396+m];
    #pragma unroll
    for (int ks = 0; ks < 8; ++ks){
        const float* pb = pp + ((size_t)ks*64 + b)*HD;
        ev += pb[268+m]; av += pb[396+m];
    }
    float e = sigmoidf(ev), ad = tanhf(av);
    float racc = 0.f;
    const int n0 = ng*64 + hh*32;
    #pragma unroll 4
    for (int i = 0; i < 32; ++i){
        int n = n0 + i;
        float wr = w_r[b*N+n], ww = w_w[b*N+n];
        size_t idx = (size_t)(b*N+n)*M + m;
        float v = Mem[idx];
        racc += wr*v;
        Mem[idx] = v*(1.f - ww*e) + ww*ad;
    }
    red[threadIdx.x] = racc; __syncthreads();
    if (hh == 0) reads_part[((size_t)ng*64 + b)*M + m] = red[m] + red[m+128];
}

// ---------- K4d: combine reads -> At rows 256..383 (+hist), pack next x rows. grid 96, 256 thr ----------
__global__ __launch_bounds__(256) void k4d_combine(
    const float* __restrict__ reads_part, const float* __restrict__ xT,
    float* __restrict__ At, float* __restrict__ hist, int t)
{
    int e = blockIdx.x*256 + threadIdx.x;
    if (blockIdx.x < 32){
        int b = e >> 7, m = e & 127;
        float s = 0.f;
        #pragma unroll
        for (int ng = 0; ng < 8; ++ng) s += reads_part[((size_t)ng*64 + b)*M + m];
        At[(size_t)(256 + m)*64 + b] = s;
        if (t >= T_READ) hist[((size_t)(t-T_READ)*K5K + 1024 + m)*64 + b] = s;
    } else {
        int e2 = e - 8192;        // 0..16383 = k*64+b for k<256
        int tn = t + 1;
        At[e2] = (tn < T_READ) ? xT[(size_t)tn*D*64 + e2] : 0.f;
    }
}

// ---------- K5: batched output GEMM over all 32 write steps. grid 256, 256 thr ----------
__global__ __launch_bounds__(256) void k5_out(
    const float* __restrict__ hist, const float* __restrict__ Wo, const float* __restrict__ bo,
    float* __restrict__ out)
{
    const int lane = threadIdx.x & 63;
    const int wid  = blockIdx.x*4 + (threadIdx.x >> 6);  // 0..1023
    const int l = wid >> 5, cg = wid & 31;
    const int j0 = cg*8;
    float acc[8] = {0.f,0.f,0.f,0.f,0.f,0.f,0.f,0.f};
    const float* hb = hist + (size_t)l*K5K*64;
    #pragma unroll 2
    for (int k = 0; k < K5K; ++k){
        float a = hb[(size_t)k*64 + lane];
        float4 w0 = *reinterpret_cast<const float4*>(Wo + (size_t)k*D + j0);
        float4 w1 = *reinterpret_cast<const float4*>(Wo + (size_t)k*D + j0 + 4);
        acc[0] += a*w0.x; acc[1] += a*w0.y; acc[2] += a*w0.z; acc[3] += a*w0.w;
        acc[4] += a*w1.x; acc[5] += a*w1.y; acc[6] += a*w1.z; acc[7] += a*w1.w;
    }
    #pragma unroll
    for (int i = 0; i < 8; ++i)
        out[((size_t)lane*L_WRITE + l)*D + j0 + i] = sigmoidf(acc[i] + bo[j0+i]);
}

extern "C" void kernel_launch(void* const* d_in, const int* in_sizes, int n_in,
                              void* d_out, int out_size, void* d_ws, size_t ws_size,
                              hipStream_t stream)
{
    const float* x   = (const float*)d_in[0];
    const float* Wl  = (const float*)d_in[1];
    const float* Ul  = (const float*)d_in[2];
    const float* bl  = (const float*)d_in[3];
    const float* Wh  = (const float*)d_in[4];
    const float* bh  = (const float*)d_in[5];
    const float* Wo  = (const float*)d_in[6];
    const float* bo  = (const float*)d_in[7];
    float* out = (float*)d_out;

    float* ws = (float*)d_ws;
    float* At         = ws; ws += (size_t)K1K*64;       // [1408][64]
    float* c_t        = ws; ws += (size_t)R*64;
    float* w_r        = ws; ws += B*N;
    float* w_w        = ws; ws += B*N;
    float* Mem        = ws; ws += (size_t)B*N*M;
    float* z_part     = ws; ws += (size_t)4*4096*64;
    float* pp         = ws; ws += (size_t)8*64*HD;
    float* mnorm      = ws; ws += B*N;
    float* dots       = ws; ws += (size_t)B*2*N;
    float* reads_part = ws; ws += (size_t)8*64*M;
    float* xT         = ws; ws += (size_t)T_READ*D*64;
    float* hist       = ws; ws += (size_t)L_WRITE*K5K*64;

    hipLaunchKernelGGL(kx_transpose, dim3(T_READ*4), dim3(256), 0, stream, x, xT);
    hipLaunchKernelGGL(k_init,       dim3(2048),     dim3(256), 0, stream, xT, At, c_t, w_r, w_w, Mem);

    for (int t = 0; t < TT; ++t){
        hipLaunchKernelGGL(k1_zgemm,    dim3(512),  dim3(256), 0, stream, At, Wl, Ul, z_part);
        hipLaunchKernelGGL(k2_gates,    dim3(256),  dim3(256), 0, stream, z_part, bl, c_t, At, hist, t);
        hipLaunchKernelGGL(k3_heads,    dim3(262),  dim3(256), 0, stream, At, Wh, pp);
        hipLaunchKernelGGL(k4a_dots,    dim3(8192), dim3(256), 0, stream, Mem, pp, bh, mnorm, dots);
        hipLaunchKernelGGL(k4b_address, dim3(128),  dim3(512), 0, stream, pp, bh, mnorm, dots, w_r, w_w);
        hipLaunchKernelGGL(k4c_rw,      dim3(512),  dim3(256), 0, stream, Mem, w_r, w_w, pp, bh, reads_part);
        hipLaunchKernelGGL(k4d_combine, dim3(96),   dim3(256), 0, stream, reads_part, xT, At, hist, t);
    }
    hipLaunchKernelGGL(k5_out, dim3(256), dim3(256), 0, stream, hist, Wo, bo, out);
}

// Round 3
// 16353.864 us; speedup vs baseline: 2.8437x; 1.1590x over previous
//
#include <hip/hip_runtime.h>
#include <math.h>

#define B 64
#define T_READ 128
#define L_WRITE 32
#define TT 160
#define D 256
#define R 1024
#define N 512
#define M 128
#define HD 524
#define K5K 1152
#define EPS 1e-8f

__device__ __forceinline__ float sigmoidf(float x){ return 1.0f/(1.0f+expf(-x)); }
__device__ __forceinline__ float softplusf(float x){ return (x > 20.f) ? x : log1pf(expf(x)); }

// ---------- one-time: transpose x -> xT[t][k][b] ----------
__global__ __launch_bounds__(256) void kx_transpose(const float* __restrict__ x, float* __restrict__ xT){
    __shared__ float tile[64][65];
    const int t = blockIdx.x >> 2, k0 = (blockIdx.x & 3)*64;
    #pragma unroll
    for (int rep = 0; rep < 16; ++rep){
        int idx = rep*256 + threadIdx.x;
        int bl = idx >> 6, kl = idx & 63;
        tile[bl][kl] = x[((size_t)bl*T_READ + t)*D + k0 + kl];
    }
    __syncthreads();
    #pragma unroll
    for (int rep = 0; rep < 16; ++rep){
        int idx = rep*256 + threadIdx.x;
        int kl = idx >> 6, bl = idx & 63;
        xT[((size_t)t*D + k0 + kl)*64 + bl] = tile[bl][kl];
    }
}

// ---------- one-time: init state ----------
__global__ void k_init(float* ht, float* readsT, float* c_t,
                       float* w_r, float* w_w, float* Mem){
    int idx = blockIdx.x*blockDim.x + threadIdx.x;
    int stride = gridDim.x*blockDim.x;
    for (int i = idx; i < B*N*M; i += stride) Mem[i] = 1e-6f;
    for (int i = idx; i < R*64;  i += stride){ ht[i]=0.f; c_t[i]=0.f; }
    for (int i = idx; i < M*64;  i += stride) readsT[i]=0.f;
    for (int i = idx; i < B*N;   i += stride){ w_r[i]=1.f/(float)N; w_w[i]=1.f/(float)N; }
}

// ---------- K1: z partials. grid 1024 = 128 colblocks x 8 ksplit, 256 thr ----------
__global__ __launch_bounds__(256) void k1_zgemm(
    const float* __restrict__ xT, const float* __restrict__ readsT, const float* __restrict__ ht,
    const float* __restrict__ Wl, const float* __restrict__ Ul,
    float* __restrict__ z_part, int t)
{
    const int lane = threadIdx.x & 63;
    const int w    = threadIdx.x >> 6;
    const int cb   = blockIdx.x >> 3;
    const int ks   = blockIdx.x & 7;
    const int j0   = cb*32 + w*8;
    const int rd   = (t < T_READ);
    const int k0   = rd ? ks*176 : 256 + ks*144;
    const int kend = rd ? k0 + 176 : k0 + 144;
    const float* xt_t = xT + (size_t)t*D*64;
    float acc[8] = {0.f,0.f,0.f,0.f,0.f,0.f,0.f,0.f};
    #pragma unroll 4
    for (int k = k0; k < kend; ++k){
        float a;
        if (k < 256)      a = xt_t[(size_t)k*64 + lane];
        else if (k < 384) a = readsT[(size_t)(k-256)*64 + lane];
        else              a = ht[(size_t)(k-384)*64 + lane];
        const float* wrow = (k < 384) ? (Wl + (size_t)k*4096) : (Ul + (size_t)(k-384)*4096);
        float4 w0 = *reinterpret_cast<const float4*>(wrow + j0);
        float4 w1 = *reinterpret_cast<const float4*>(wrow + j0 + 4);
        acc[0] += a*w0.x; acc[1] += a*w0.y; acc[2] += a*w0.z; acc[3] += a*w0.w;
        acc[4] += a*w1.x; acc[5] += a*w1.y; acc[6] += a*w1.z; acc[7] += a*w1.w;
    }
    #pragma unroll
    for (int i = 0; i < 8; ++i)
        z_part[((size_t)ks*4096 + (j0+i))*64 + lane] = acc[i];
}

// ---------- K2: combine z partials + LSTM cell. grid 256, 256 thr ----------
__global__ __launch_bounds__(256) void k2_gates(
    const float* __restrict__ zp, const float* __restrict__ bl,
    float* __restrict__ c_t, float* __restrict__ ht, float* __restrict__ hist, int t)
{
    const int b = threadIdx.x & 63;
    const int r = blockIdx.x*4 + (threadIdx.x >> 6);
    float g4[4];
    #pragma unroll
    for (int g = 0; g < 4; ++g){
        int col = r + g*1024;
        float s = bl[col];
        #pragma unroll
        for (int ks = 0; ks < 8; ++ks) s += zp[((size_t)ks*4096 + col)*64 + b];
        g4[g] = s;
    }
    float cn = sigmoidf(g4[1])*c_t[r*64+b] + sigmoidf(g4[0])*tanhf(g4[2]);
    float hn = sigmoidf(g4[3])*tanhf(cn);
    c_t[r*64+b] = cn;
    ht[(size_t)r*64 + b] = hn;
    if (t >= T_READ) hist[((size_t)(t-T_READ)*K5K + r)*64 + b] = hn;
}

// ---------- K3: head-param partials pp[ks][col][b]. grid 262, 256 thr ----------
__global__ __launch_bounds__(256) void k3_heads(
    const float* __restrict__ ht, const float* __restrict__ Wh, float* __restrict__ pp)
{
    const int lane = threadIdx.x & 63;
    const int wid  = blockIdx.x*4 + (threadIdx.x >> 6);   // 0..1047
    const int cg = wid % 131, ks = wid / 131;
    const int j0 = cg*4;
    const int k0 = ks*128;
    float ax=0.f, ay=0.f, az=0.f, aw=0.f;
    #pragma unroll 4
    for (int k = k0; k < k0+128; ++k){
        float a = ht[(size_t)k*64 + lane];
        float4 wv = *reinterpret_cast<const float4*>(Wh + (size_t)k*HD + j0);
        ax += a*wv.x; ay += a*wv.y; az += a*wv.z; aw += a*wv.w;
    }
    pp[((size_t)ks*HD + j0+0)*64 + lane] = ax;
    pp[((size_t)ks*HD + j0+1)*64 + lane] = ay;
    pp[((size_t)ks*HD + j0+2)*64 + lane] = az;
    pp[((size_t)ks*HD + j0+3)*64 + lane] = aw;
}

// ---------- K3b: finalize head params (khat/scal/ea). grid 131, 256 thr ----------
__global__ __launch_bounds__(256) void k3b_final(
    const float* __restrict__ pp, const float* __restrict__ bh,
    float* __restrict__ khat, float* __restrict__ scal, float* __restrict__ ea)
{
    const int b   = threadIdx.x & 63;
    const int col = blockIdx.x*4 + (threadIdx.x >> 6);   // 0..523
    float v = bh[col];
    #pragma unroll
    for (int ks = 0; ks < 8; ++ks) v += pp[((size_t)ks*HD + col)*64 + b];
    if (col < 128)       khat[b*256 + col] = tanhf(v);
    else if (col < 134){
        int i = col - 128;
        float o = (i==0) ? softplusf(v) : (i==1) ? sigmoidf(v) : (i==5) ? 1.0f+softplusf(v) : v;
        scal[b*12 + i] = o;
    }
    else if (col < 262)  khat[b*256 + 128 + (col-134)] = tanhf(v);
    else if (col < 268){
        int i = col - 262;
        float o = (i==0) ? softplusf(v) : (i==1) ? sigmoidf(v) : (i==5) ? 1.0f+softplusf(v) : v;
        scal[b*12 + 6 + i] = o;
    }
    else if (col < 396)  ea[b*256 + (col-268)] = sigmoidf(v);
    else                 ea[b*256 + 128 + (col-396)] = tanhf(v);
}

// ---------- K4a: Mem row norms + content dots. grid 8192, 256 thr ----------
__global__ __launch_bounds__(256) void k4a_dots(
    const float* __restrict__ Mem, const float* __restrict__ khat,
    float* __restrict__ mnorm, float* __restrict__ dots)
{
    const int wid  = blockIdx.x*4 + (threadIdx.x >> 6);
    const int lane = threadIdx.x & 63;
    const int b = wid >> 9, n = wid & 511;
    const float* mrow = Mem + (size_t)(b*N + n)*M;
    float2 mv = *reinterpret_cast<const float2*>(mrow + lane*2);
    float2 kr = *reinterpret_cast<const float2*>(khat + b*256 + lane*2);
    float2 kw = *reinterpret_cast<const float2*>(khat + b*256 + 128 + lane*2);
    float s2 = mv.x*mv.x + mv.y*mv.y;
    float dr = mv.x*kr.x + mv.y*kr.y;
    float dw = mv.x*kw.x + mv.y*kw.y;
    #pragma unroll
    for (int off = 32; off; off >>= 1){
        s2 += __shfl_xor(s2, off);
        dr += __shfl_xor(dr, off);
        dw += __shfl_xor(dw, off);
    }
    if (lane == 0){
        mnorm[b*N + n] = sqrtf(s2);
        dots[(b*2+0)*N + n] = dr;
        dots[(b*2+1)*N + n] = dw;
    }
}

// ---------- K4b: addressing. grid 128 (b,head), 512 thr ----------
__device__ __forceinline__ float blk_sum8(float v, float* red8, int lane, int wv){
    #pragma unroll
    for (int off = 32; off; off >>= 1) v += __shfl_xor(v, off);
    if (lane == 0) red8[wv] = v;
    __syncthreads();
    float r = red8[0]+red8[1]+red8[2]+red8[3]+red8[4]+red8[5]+red8[6]+red8[7];
    __syncthreads();
    return r;
}
__device__ __forceinline__ float blk_max8(float v, float* red8, int lane, int wv){
    #pragma unroll
    for (int off = 32; off; off >>= 1) v = fmaxf(v, __shfl_xor(v, off));
    if (lane == 0) red8[wv] = v;
    __syncthreads();
    float r = fmaxf(fmaxf(fmaxf(red8[0],red8[1]),fmaxf(red8[2],red8[3])),
                    fmaxf(fmaxf(red8[4],red8[5]),fmaxf(red8[6],red8[7])));
    __syncthreads();
    return r;
}

__global__ __launch_bounds__(512) void k4b_address(
    const float* __restrict__ khat, const float* __restrict__ scal,
    const float* __restrict__ mnorm, const float* __restrict__ dots,
    float* __restrict__ w_r, float* __restrict__ w_w)
{
    __shared__ float red8[8];
    __shared__ float wg[512];
    const int b = blockIdx.x >> 1, head = blockIdx.x & 1;
    const int n = threadIdx.x;
    const int lane = n & 63, wv = n >> 6;

    float kv = (n < 128) ? khat[b*256 + head*128 + n] : 0.f;
    float kn = sqrtf(blk_sum8(kv*kv, red8, lane, wv));

    const float* sc = scal + b*12 + head*6;
    float beta = sc[0], g = sc[1], gamma = sc[5];
    float s0r = sc[2], s1r = sc[3], s2r = sc[4];
    float smx = fmaxf(s0r, fmaxf(s1r, s2r));
    float e0 = expf(s0r-smx), e1 = expf(s1r-smx), e2 = expf(s2r-smx);
    float esum = e0+e1+e2;
    float s0 = e0/esum, s1 = e1/esum, s2 = e2/esum;

    float sim = dots[(b*2+head)*N + n] / (mnorm[b*N + n]*kn + EPS);
    float a = beta * sim;
    float amax = blk_max8(a, red8, lane, wv);
    float ev = expf(a - amax);
    float wc = ev / blk_sum8(ev, red8, lane, wv);

    float* wbuf = head ? w_w : w_r;
    float wprev = wbuf[b*N + n];
    float wgv = g*wc + (1.0f - g)*wprev;
    wg[n] = wgv; __syncthreads();
    float wsv = s0*wg[(n+1)&511] + s1*wgv + s2*wg[(n-1)&511];
    float wp = powf(wsv + EPS, gamma);
    float wsum = blk_sum8(wp, red8, lane, wv);
    wbuf[b*N + n] = wp / wsum;
}

// ---------- K4c: read (old Mem) + erase/add update + reads finalize. grid 256 = 64 b x 4 mg, 256 thr ----------
__global__ __launch_bounds__(256) void k4c_rw(
    float* __restrict__ Mem, const float* __restrict__ w_r, const float* __restrict__ w_w,
    const float* __restrict__ ea, float* __restrict__ readsT, float* __restrict__ hist, int t)
{
    __shared__ float wls[512], wws[512];
    __shared__ float red[256];
    const int b = blockIdx.x >> 2, mg = blockIdx.x & 3;
    const int m_l = threadIdx.x & 31, ng = threadIdx.x >> 5;
    const int m = mg*32 + m_l;
    wls[threadIdx.x]       = w_r[b*N + threadIdx.x];
    wls[threadIdx.x + 256] = w_r[b*N + threadIdx.x + 256];
    wws[threadIdx.x]       = w_w[b*N + threadIdx.x];
    wws[threadIdx.x + 256] = w_w[b*N + threadIdx.x + 256];
    const float e  = ea[b*256 + m];
    const float ad = ea[b*256 + 128 + m];
    __syncthreads();
    float racc = 0.f;
    #pragma unroll 4
    for (int i = 0; i < 64; ++i){
        int n = i*8 + ng;
        size_t idx = ((size_t)(b*N) + n)*M + m;
        float v = Mem[idx];
        float wr = wls[n], ww = wws[n];
        racc += wr*v;
        Mem[idx] = v*(1.f - ww*e) + ww*ad;
    }
    red[threadIdx.x] = racc; __syncthreads();
    if (threadIdx.x < 32){
        float s = 0.f;
        #pragma unroll
        for (int g = 0; g < 8; ++g) s += red[g*32 + threadIdx.x];
        int mm = mg*32 + threadIdx.x;
        readsT[(size_t)mm*64 + b] = s;
        if (t >= T_READ) hist[((size_t)(t-T_READ)*K5K + 1024 + mm)*64 + b] = s;
    }
}

// ---------- K5: batched output GEMM over all 32 write steps. grid 512, 256 thr ----------
__global__ __launch_bounds__(256) void k5_out(
    const float* __restrict__ hist, const float* __restrict__ Wo, const float* __restrict__ bo,
    float* __restrict__ out)
{
    const int lane = threadIdx.x & 63;
    const int wid  = blockIdx.x*4 + (threadIdx.x >> 6);  // 0..2047
    const int l = wid >> 6, cg = wid & 63;
    const int j0 = cg*4;
    float acc[4] = {0.f,0.f,0.f,0.f};
    const float* hb = hist + (size_t)l*K5K*64;
    #pragma unroll 4
    for (int k = 0; k < K5K; ++k){
        float a = hb[(size_t)k*64 + lane];
        float4 wv = *reinterpret_cast<const float4*>(Wo + (size_t)k*D + j0);
        acc[0] += a*wv.x; acc[1] += a*wv.y; acc[2] += a*wv.z; acc[3] += a*wv.w;
    }
    #pragma unroll
    for (int i = 0; i < 4; ++i)
        out[((size_t)lane*L_WRITE + l)*D + j0 + i] = sigmoidf(acc[i] + bo[j0+i]);
}

extern "C" void kernel_launch(void* const* d_in, const int* in_sizes, int n_in,
                              void* d_out, int out_size, void* d_ws, size_t ws_size,
                              hipStream_t stream)
{
    const float* x   = (const float*)d_in[0];
    const float* Wl  = (const float*)d_in[1];
    const float* Ul  = (const float*)d_in[2];
    const float* bl  = (const float*)d_in[3];
    const float* Wh  = (const float*)d_in[4];
    const float* bh  = (const float*)d_in[5];
    const float* Wo  = (const float*)d_in[6];
    const float* bo  = (const float*)d_in[7];
    float* out = (float*)d_out;

    float* ws = (float*)d_ws;
    float* xT     = ws; ws += (size_t)T_READ*D*64;     // 2.10M
    float* ht     = ws; ws += (size_t)R*64;
    float* readsT = ws; ws += (size_t)M*64;
    float* c_t    = ws; ws += (size_t)R*64;
    float* w_r    = ws; ws += B*N;
    float* w_w    = ws; ws += B*N;
    float* Mem    = ws; ws += (size_t)B*N*M;           // 4.19M
    float* z_part = ws; ws += (size_t)8*4096*64;       // 2.10M
    float* pp     = ws; ws += (size_t)8*HD*64;         // 268K
    float* khat   = ws; ws += (size_t)B*256;
    float* scal   = ws; ws += (size_t)B*12;
    float* ea     = ws; ws += (size_t)B*256;
    float* mnorm  = ws; ws += B*N;
    float* dots   = ws; ws += (size_t)B*2*N;
    float* hist   = ws; ws += (size_t)L_WRITE*K5K*64;  // 2.36M

    hipLaunchKernelGGL(kx_transpose, dim3(T_READ*4), dim3(256), 0, stream, x, xT);
    hipLaunchKernelGGL(k_init,       dim3(2048),     dim3(256), 0, stream, ht, readsT, c_t, w_r, w_w, Mem);

    for (int t = 0; t < TT; ++t){
        hipLaunchKernelGGL(k1_zgemm,    dim3(1024), dim3(256), 0, stream, xT, readsT, ht, Wl, Ul, z_part, t);
        hipLaunchKernelGGL(k2_gates,    dim3(256),  dim3(256), 0, stream, z_part, bl, c_t, ht, hist, t);
        hipLaunchKernelGGL(k3_heads,    dim3(262),  dim3(256), 0, stream, ht, Wh, pp);
        hipLaunchKernelGGL(k3b_final,   dim3(131),  dim3(256), 0, stream, pp, bh, khat, scal, ea);
        hipLaunchKernelGGL(k4a_dots,    dim3(8192), dim3(256), 0, stream, Mem, khat, mnorm, dots);
        hipLaunchKernelGGL(k4b_address, dim3(128),  dim3(512), 0, stream, khat, scal, mnorm, dots, w_r, w_w);
        hipLaunchKernelGGL(k4c_rw,      dim3(256),  dim3(256), 0, stream, Mem, w_r, w_w, ea, readsT, hist, t);
    }
    hipLaunchKernelGGL(k5_out, dim3(512), dim3(256), 0, stream, hist, Wo, bo, out);
}